// Round 4
// baseline (714.822 us; speedup 1.0000x reference)
//
#include <hip/hip_runtime.h>

// ChebyshevKAN on MI355X (gfx950).
// Reformulation: einsum(bid,oid->bo) + x@base_w.T  ==  Xaug @ W^T with
//   Xaug[b, i*6+d] = T_{d+1}(tanh(x_i))  (d=0..4),  Xaug[b, i*6+5] = x_i
//   W[o,    i*6+d] = coeff[o,i,d+1]      (d=0..4),  W[o,    i*6+5] = base_w[o,i]
// T0==1 slice folds into bias:  bias'[o] = bias[o] + sum_i coeff[o,i,0].
//
// R9: minimal-sync software-pipelined GEMM (one barrier + one combined
// s_waitcnt per BK=32 K-step; frag ds_reads are compiler-visible so hipcc
// emits its own counted lgkm waits -- no asm choreography, no sched_barrier).
// Body(t):  waitcnt(vm0,lgkm0); s_barrier;
//           reads(t+1)->other bank   (overlaps this body's MFMA)
//           stage(t+2)->buf[t%2]     (lands by next body's top-wait)
//           MFMA(t) from current bank
// Hazards: lgkm0-before-barrier => all waves' reads(t) done before stage(t+2)
// overwrite (WAR); vm0+barrier publishes stage(t+1) before reads(t+1) (RAW).
// Register ledger (R7 spill lesson): acc 128 + 2 banks x 48 + ~20 addr ~= 246
// <= 256 cap at 2 waves/SIMD -> no spill (watch WRITE_SIZE).
// 64B-row LDS swizzle: chunk ^= (row>>1)&3  (row&3 leaves 4-way conflicts;
// >>1 gives 2-way max within each 16-lane quarter-wave = free per m136).

typedef __bf16 bf16x8 __attribute__((ext_vector_type(8)));
typedef float f32x4 __attribute__((ext_vector_type(4)));
typedef unsigned short u16x8 __attribute__((ext_vector_type(8)));

__device__ __forceinline__ unsigned short f2bf(float f) {
    unsigned int u = __float_as_uint(f);
    unsigned int r = (u + 0x7FFFu + ((u >> 16) & 1u)) >> 16;
    return (unsigned short)r;
}
__device__ __forceinline__ float bf2f(unsigned short b) {
    return __uint_as_float(((unsigned int)b) << 16);
}

__device__ __forceinline__ float fast_tanh(float x) {
    float a = fminf(fmaxf(x, -15.f), 15.f);
    float e = __expf(2.f * a);
    return 1.f - 2.f * __builtin_amdgcn_rcpf(e + 1.f);
}
__device__ __forceinline__ float fast_silu(float y) {
    float a = fminf(fmaxf(y, -30.f), 30.f);
    return y * __builtin_amdgcn_rcpf(1.f + __expf(-a));
}

__device__ __forceinline__ void cheb_pack(float s, unsigned short* o6) {
    float u  = fast_tanh(s);
    float T1 = u;
    float T2 = 2.f * u * u - 1.f;
    float T3 = 2.f * u * T2 - T1;
    float T4 = 2.f * u * T3 - T2;
    float T5 = 2.f * u * T4 - T3;
    o6[0] = f2bf(T1); o6[1] = f2bf(T2); o6[2] = f2bf(T3);
    o6[3] = f2bf(T4); o6[4] = f2bf(T5); o6[5] = f2bf(s);
}

__device__ __forceinline__ void load_lds16(const void* g, void* l) {
    __builtin_amdgcn_global_load_lds(
        (const __attribute__((address_space(1))) void*)g,
        (__attribute__((address_space(3))) void*)l, 16, 0, 0);
}

// ---------------- prep: weights [O,I,6]+[O,I] -> W[N=O, K=I*6] bf16 ----------
__global__ __launch_bounds__(256) void prep_w_kernel(
    const float* __restrict__ coeff, const float* __restrict__ base_w,
    unsigned short* __restrict__ W, int OI)
{
    int idx = blockIdx.x * 256 + threadIdx.x;
    if (idx >= OI) return;
    const float* c = coeff + (size_t)idx * 6;
    unsigned short w0 = f2bf(c[1]), w1 = f2bf(c[2]), w2 = f2bf(c[3]),
                   w3 = f2bf(c[4]), w4 = f2bf(c[5]), w5 = f2bf(base_w[idx]);
    unsigned int* d = (unsigned int*)(W + (size_t)idx * 6);
    d[0] = w0 | ((unsigned int)w1 << 16);
    d[1] = w2 | ((unsigned int)w3 << 16);
    d[2] = w4 | ((unsigned int)w5 << 16);
}

__global__ __launch_bounds__(256) void prep_bias_kernel(
    const float* __restrict__ coeff, const float* __restrict__ bias,
    float* __restrict__ bp, int I)
{
    int o = blockIdx.x, tid = threadIdx.x;
    float s = 0.f;
    for (int i = tid; i < I; i += 256) s += coeff[((size_t)o * I + i) * 6];
    #pragma unroll
    for (int off = 32; off > 0; off >>= 1) s += __shfl_down(s, off);
    __shared__ float red[4];
    int lane = tid & 63, wv = tid >> 6;
    if (lane == 0) red[wv] = s;
    __syncthreads();
    if (tid == 0) bp[o] = bias[o] + red[0] + red[1] + red[2] + red[3];
}

// ---------------- expand1: x[b,1024] -> Xaug[b,6144] bf16  (block per row) ---
__global__ __launch_bounds__(256) void expand1_kernel(
    const float* __restrict__ x, unsigned short* __restrict__ Xa)
{
    int b = blockIdx.x, tid = threadIdx.x;
    f32x4 xv = *(const f32x4*)(x + (size_t)b * 1024 + tid * 4);
    alignas(16) unsigned short ov[24];
    #pragma unroll
    for (int e = 0; e < 4; e++) cheb_pack(fast_tanh(xv[e]), ov + e * 6);
    u16x8* dst = (u16x8*)(Xa + (size_t)b * 6144 + tid * 24);
    const u16x8* src = (const u16x8*)ov;
    dst[0] = src[0]; dst[1] = src[1]; dst[2] = src[2];
}

// ------------- LN + SiLU + expand2 fused (block per row of 1024, h in bf16) --
__global__ __launch_bounds__(256) void ln_silu_expand_kernel(
    const unsigned short* __restrict__ H, const float* __restrict__ gamma,
    const float* __restrict__ beta, unsigned short* __restrict__ Xa)
{
    int b = blockIdx.x, tid = threadIdx.x;
    ushort4 hb = *(const ushort4*)(H + (size_t)b * 1024 + tid * 4);
    float hv[4] = { bf2f(hb.x), bf2f(hb.y), bf2f(hb.z), bf2f(hb.w) };
    float s1 = hv[0] + hv[1] + hv[2] + hv[3];
    float s2 = hv[0]*hv[0] + hv[1]*hv[1] + hv[2]*hv[2] + hv[3]*hv[3];
    #pragma unroll
    for (int off = 32; off > 0; off >>= 1) {
        s1 += __shfl_down(s1, off);
        s2 += __shfl_down(s2, off);
    }
    __shared__ float red[8];
    __shared__ float stats[2];
    int lane = tid & 63, wv = tid >> 6;
    if (lane == 0) { red[wv] = s1; red[4 + wv] = s2; }
    __syncthreads();
    if (tid == 0) {
        float t1 = red[0] + red[1] + red[2] + red[3];
        float t2 = red[4] + red[5] + red[6] + red[7];
        float mu = t1 * (1.f / 1024.f);
        float var = t2 * (1.f / 1024.f) - mu * mu;
        stats[0] = mu;
        stats[1] = rsqrtf(var + 1e-5f);
    }
    __syncthreads();
    float mu = stats[0], rs = stats[1];
    f32x4 g  = *(const f32x4*)(gamma + tid * 4);
    f32x4 bt = *(const f32x4*)(beta  + tid * 4);
    alignas(16) unsigned short ov[24];
    #pragma unroll
    for (int e = 0; e < 4; e++) {
        float y = (hv[e] - mu) * rs * g[e] + bt[e];
        cheb_pack(fast_silu(y), ov + e * 6);
    }
    u16x8* dst = (u16x8*)(Xa + (size_t)b * 6144 + tid * 24);
    const u16x8* src = (const u16x8*)ov;
    dst[0] = src[0]; dst[1] = src[1]; dst[2] = src[2];
}

// ======= pipelined bf16 GEMM: C[M,N] = A[M,K]*W[N,K]^T + bias (BK=32) =======
// 256 x BN tile, 8 waves (2M x 4N), wave tile 128 x (BN/4).

#define WAITTOP() do { \
    asm volatile("s_waitcnt vmcnt(0) lgkmcnt(0)" ::: "memory"); \
    __builtin_amdgcn_s_barrier(); } while (0)

template<int BN, bool OUT_BF16>
__global__ __launch_bounds__(512, 2) void gemm3_kernel(
    const unsigned short* __restrict__ A,   // [M,K] bf16 bits
    const unsigned short* __restrict__ Wt,  // [N,K] bf16 bits
    const float* __restrict__ bias,         // [N]
    void* __restrict__ Cout,                // [M,N] bf16 or f32
    int N, int K, int NMT)
{
    constexpr int FN  = BN / 64;        // B frags per wave (4 or 2)
    constexpr int ASZ = 256 * 32;       // shorts per A buffer (16 KB)
    constexpr int BSZ = BN * 32;        // shorts per B buffer
    __shared__ __align__(16) unsigned short As[2 * ASZ];
    __shared__ __align__(16) unsigned short Bs[2 * BSZ];

    const int tid  = threadIdx.x;
    const int lane = tid & 63;
    const int wave = tid >> 6;
    const int wm   = wave >> 2;         // 0..1
    const int wn   = wave & 3;          // 0..3

    // bijective XCD swizzle (grid % 8 == 0 here)
    int wg = blockIdx.x;
    {
        const int nwg = gridDim.x;
        if ((nwg & 7) == 0) { const int cpx = nwg >> 3; wg = (wg & 7) * cpx + (wg >> 3); }
    }
    const int mt = wg % NMT;
    const int nt = wg / NMT;
    const size_t m0 = (size_t)mt * 256;
    const size_t n0 = (size_t)nt * BN;

    // ---- staging addressing: pre-swizzled global src, linear LDS dest ----
    // 16-row unit u; thread covers (row = u*16 + lane/4, chunk = lane%4),
    // src chunk = (lane&3) ^ ((row>>1)&3) = (lane&3) ^ ((lane>>3)&3).
    const int cs   = (((lane & 3) ^ ((lane >> 3) & 3)) << 3);  // shorts
    const int srow = lane >> 2;
    const unsigned short* AgJ0 = A + (m0 + (size_t)((wave * 2 + 0) * 16 + srow)) * K + cs;
    const unsigned short* AgJ1 = A + (m0 + (size_t)((wave * 2 + 1) * 16 + srow)) * K + cs;
    const unsigned short* BgJ0 = Wt + (n0 + (size_t)((wave * (BN / 128) + 0) * 16 + srow)) * K + cs;
    const unsigned short* BgJ1 = (BN == 256)
        ? Wt + (n0 + (size_t)((wave * 2 + 1) * 16 + srow)) * K + cs : BgJ0;
    unsigned short* AD0 = As + (wave * 2 + 0) * 512 + lane * 8;
    unsigned short* AD1 = As + (wave * 2 + 1) * 512 + lane * 8;
    unsigned short* BD0 = Bs + (wave * (BN / 128) + 0) * 512 + lane * 8;
    unsigned short* BD1 = Bs + (wave * 2 + 1) * 512 + lane * 8;   // used only BN=256

    // ---- frag-read bases (XOR de-swizzle on read; key = (row>>1)&3) ----
    const int fr = lane & 15;
    const int cg = lane >> 4;
    const int ck = ((cg ^ ((fr >> 1) & 3)) << 3);               // shorts
    const unsigned short* PA = As + (wm * 128 + fr) * 32 + ck;
    const unsigned short* PB = Bs + (wn * (BN / 4) + fr) * 32 + ck;

    const int NT = K >> 5;              // 32-wide K-tiles (192 here, even)

    f32x4 acc[2][4][FN];
    #pragma unroll
    for (int mh = 0; mh < 2; ++mh)
        #pragma unroll
        for (int mf = 0; mf < 4; ++mf)
            #pragma unroll
            for (int nf = 0; nf < FN; ++nf)
                acc[mh][mf][nf] = f32x4{0.f, 0.f, 0.f, 0.f};

    bf16x8 aF[8], aG[8], bF[FN], bG[FN];

#define STAGE(T, B_) do { \
    const size_t ko_ = (size_t)(T) * 32; \
    load_lds16(AgJ0 + ko_, AD0 + (B_) * ASZ); \
    load_lds16(AgJ1 + ko_, AD1 + (B_) * ASZ); \
    load_lds16(BgJ0 + ko_, BD0 + (B_) * BSZ); \
    if constexpr (BN == 256) load_lds16(BgJ1 + ko_, BD1 + (B_) * BSZ); \
} while (0)

#define RD(AF_, BF_, B_) do { \
    _Pragma("unroll") \
    for (int mh = 0; mh < 2; ++mh) \
        _Pragma("unroll") \
        for (int mf = 0; mf < 4; ++mf) \
            AF_[mh * 4 + mf] = *(const bf16x8*)(PA + (B_) * ASZ + (mh * 64 + mf * 16) * 32); \
    _Pragma("unroll") \
    for (int nf = 0; nf < FN; ++nf) \
        BF_[nf] = *(const bf16x8*)(PB + (B_) * BSZ + nf * 16 * 32); \
} while (0)

#define MM(AF_, BF_) do { \
    _Pragma("unroll") \
    for (int mh = 0; mh < 2; ++mh) \
        _Pragma("unroll") \
        for (int mf = 0; mf < 4; ++mf) \
            _Pragma("unroll") \
            for (int nf = 0; nf < FN; ++nf) \
                acc[mh][mf][nf] = __builtin_amdgcn_mfma_f32_16x16x32_bf16( \
                    AF_[mh * 4 + mf], BF_[nf], acc[mh][mf][nf], 0, 0, 0); \
} while (0)

    // prologue: stage T0->buf0, T1->buf1; drain T0 only; read frags(T0)
    STAGE(0, 0);
    STAGE(1, 1);
    if constexpr (BN == 256) asm volatile("s_waitcnt vmcnt(4)" ::: "memory");
    else                     asm volatile("s_waitcnt vmcnt(3)" ::: "memory");
    __builtin_amdgcn_s_barrier();
    RD(aF, bF, 0);

    // main: body(t even) + body(t odd); stage depth 1 body, read depth 1 body
    for (int t = 0; t < NT - 2; t += 2) {
        WAITTOP();              // drains stage(t+1) + reads(t); publishes buf1
        RD(aG, bG, 1);          // frags(t+1)  (overlap with MM below)
        STAGE(t + 2, 0);        // buf0 free: reads(t) done in all waves
        MM(aF, bF);             // MFMA(t)
        WAITTOP();
        RD(aF, bF, 0);
        STAGE(t + 3, 1);
        MM(aG, bG);
    }
    // tail: t = NT-2, NT-1 (no more staging)
    WAITTOP();
    RD(aG, bG, 1);
    MM(aF, bF);
    WAITTOP();
    MM(aG, bG);

#undef STAGE
#undef RD
#undef MM

    // C/D layout (verified): col = lane&15, row = (lane>>4)*4 + reg
    const size_t rbase0 = m0 + wm * 128 + ((lane >> 4) << 2);
    const int cb = lane & 15;
    int colg[FN]; float bv[FN];
    #pragma unroll
    for (int nf = 0; nf < FN; ++nf) {
        colg[nf] = (int)n0 + wn * (BN / 4) + nf * 16 + cb;
        bv[nf] = bias[colg[nf]];
    }
    #pragma unroll
    for (int mh = 0; mh < 2; ++mh)
        #pragma unroll
        for (int mf = 0; mf < 4; ++mf) {
            const size_t rg0 = rbase0 + mh * 64 + mf * 16;
            #pragma unroll
            for (int r = 0; r < 4; ++r) {
                const size_t rowoff = (rg0 + r) * (size_t)N;
                #pragma unroll
                for (int nf = 0; nf < FN; ++nf) {
                    const float v = acc[mh][mf][nf][r] + bv[nf];
                    if constexpr (OUT_BF16)
                        ((unsigned short*)Cout)[rowoff + colg[nf]] = f2bf(v);
                    else
                        ((float*)Cout)[rowoff + colg[nf]] = v;
                }
            }
        }
}

extern "C" void kernel_launch(void* const* d_in, const int* in_sizes, int n_in,
                              void* d_out, int out_size, void* d_ws, size_t ws_size,
                              hipStream_t stream)
{
    const float* x       = (const float*)d_in[0];
    const float* coeff1  = (const float*)d_in[1];
    const float* base_w1 = (const float*)d_in[2];
    const float* bias1   = (const float*)d_in[3];
    const float* gamma   = (const float*)d_in[4];
    const float* beta    = (const float*)d_in[5];
    const float* coeff2  = (const float*)d_in[6];
    const float* base_w2 = (const float*)d_in[7];
    const float* bias2   = (const float*)d_in[8];
    float* out = (float*)d_out;

    const int B = 16384, D0 = 1024, D1 = 1024, D2 = 512;
    const int K1 = D0 * 6, K2 = D1 * 6;   // 6144 each

    char* base = (char*)d_ws;
    size_t off = 0;
    unsigned short* W1 = (unsigned short*)(base + off); off += (size_t)D1 * K1 * 2;
    unsigned short* W2 = (unsigned short*)(base + off); off += (size_t)D2 * K2 * 2;
    float* b1p = (float*)(base + off); off += (size_t)D1 * 4;
    float* b2p = (float*)(base + off); off += (size_t)D2 * 4;
    off = (off + 255) & ~(size_t)255;

    size_t per_row = (size_t)K1 * 2 + (size_t)D1 * 2;   // 14336 B
    long long avail = (long long)ws_size - (long long)off;
    long long mcl = avail > 0 ? avail / (long long)per_row : 0;
    int Mc = (int)((mcl / 256) * 256);
    if (Mc < 256) Mc = 256;
    if (Mc > B) Mc = B;

    unsigned short* Xa = (unsigned short*)(base + off);
    unsigned short* h = (unsigned short*)(base + off + (size_t)Mc * K1 * 2);

    prep_w_kernel<<<(D1 * D0 + 255) / 256, 256, 0, stream>>>(coeff1, base_w1, W1, D1 * D0);
    prep_w_kernel<<<(D2 * D1 + 255) / 256, 256, 0, stream>>>(coeff2, base_w2, W2, D2 * D1);
    prep_bias_kernel<<<D1, 256, 0, stream>>>(coeff1, bias1, b1p, D0);
    prep_bias_kernel<<<D2, 256, 0, stream>>>(coeff2, bias2, b2p, D1);

    for (int m0 = 0; m0 < B; m0 += Mc) {
        int rows = (B - m0 < Mc) ? (B - m0) : Mc;
        int nmt = rows / 256;
        expand1_kernel<<<rows, 256, 0, stream>>>(x + (size_t)m0 * D0, Xa);
        gemm3_kernel<256, true><<<nmt * (D1 / 256), 512, 0, stream>>>(
            Xa, W1, b1p, h, D1, K1, nmt);
        ln_silu_expand_kernel<<<rows, 256, 0, stream>>>(h, gamma, beta, Xa);
        gemm3_kernel<128, false><<<nmt * (D2 / 128), 512, 0, stream>>>(
            Xa, W2, b2p, out + (size_t)m0 * D2, D2, K2, nmt);
    }
}

// Round 5
// 650.102 us; speedup vs baseline: 1.0996x; 1.0996x over previous
//
#include <hip/hip_runtime.h>

// ChebyshevKAN on MI355X (gfx950).
// Reformulation: einsum(bid,oid->bo) + x@base_w.T  ==  Xaug @ W^T with
//   Xaug[b, i*6+d] = T_{d+1}(tanh(x_i))  (d=0..4),  Xaug[b, i*6+5] = x_i
//   W[o,    i*6+d] = coeff[o,i,d+1]      (d=0..4),  W[o,    i*6+5] = base_w[o,i]
// T0==1 slice folds into bias:  bias'[o] = bias[o] + sum_i coeff[o,i,0].
//
// R10: R9's 30% MfmaUtil was the top-of-body vmcnt(0) draining the stage
// issued ONE body (~330 cyc) earlier, vs ~200-900 cyc load latency ->
// every body stalls. Same defect retro-explains R0/R6 (~34%). Fix = T4
// (counted vmcnt, never 0 in main loop): ring-4 LDS K-tile buffers,
// stage(t+4) issued at body t, drained at body t+3's counted wait ->
// 3-body (~1000 cyc) prefetch distance.
// Body t: s_waitcnt vmcnt(2*LPS) lgkmcnt(0); s_barrier;      [drains stage t+1]
//         RD frags(t+1) <- ring[(t+1)&3]; STAGE(t+4 -> ring[t&3]); MM(t)
// WAR: ring[t&3] last read at body t-1; lgkm0+barrier at top of body t
//      completes all waves' reads before stage(t+4)'s writes land.
// RAW: counted vmcnt drains exactly stage(t+1); barrier publishes x-wave.
// Unroll x4 -> all ring indices compile-time (no scratch, rule #20).
// Register ledger: acc 128 AGPR + 24 frags x 4 = 96 VGPR + addr -> no spill
// (R7 spill lesson; verify WRITE_SIZE stays 32768).

typedef __bf16 bf16x8 __attribute__((ext_vector_type(8)));
typedef float f32x4 __attribute__((ext_vector_type(4)));
typedef unsigned short u16x8 __attribute__((ext_vector_type(8)));

__device__ __forceinline__ unsigned short f2bf(float f) {
    unsigned int u = __float_as_uint(f);
    unsigned int r = (u + 0x7FFFu + ((u >> 16) & 1u)) >> 16;
    return (unsigned short)r;
}
__device__ __forceinline__ float bf2f(unsigned short b) {
    return __uint_as_float(((unsigned int)b) << 16);
}

__device__ __forceinline__ float fast_tanh(float x) {
    float a = fminf(fmaxf(x, -15.f), 15.f);
    float e = __expf(2.f * a);
    return 1.f - 2.f * __builtin_amdgcn_rcpf(e + 1.f);
}
__device__ __forceinline__ float fast_silu(float y) {
    float a = fminf(fmaxf(y, -30.f), 30.f);
    return y * __builtin_amdgcn_rcpf(1.f + __expf(-a));
}

__device__ __forceinline__ void cheb_pack(float s, unsigned short* o6) {
    float u  = fast_tanh(s);
    float T1 = u;
    float T2 = 2.f * u * u - 1.f;
    float T3 = 2.f * u * T2 - T1;
    float T4 = 2.f * u * T3 - T2;
    float T5 = 2.f * u * T4 - T3;
    o6[0] = f2bf(T1); o6[1] = f2bf(T2); o6[2] = f2bf(T3);
    o6[3] = f2bf(T4); o6[4] = f2bf(T5); o6[5] = f2bf(s);
}

__device__ __forceinline__ void load_lds16(const void* g, void* l) {
    __builtin_amdgcn_global_load_lds(
        (const __attribute__((address_space(1))) void*)g,
        (__attribute__((address_space(3))) void*)l, 16, 0, 0);
}

// ---------------- prep: weights [O,I,6]+[O,I] -> W[N=O, K=I*6] bf16 ----------
__global__ __launch_bounds__(256) void prep_w_kernel(
    const float* __restrict__ coeff, const float* __restrict__ base_w,
    unsigned short* __restrict__ W, int OI)
{
    int idx = blockIdx.x * 256 + threadIdx.x;
    if (idx >= OI) return;
    const float* c = coeff + (size_t)idx * 6;
    unsigned short w0 = f2bf(c[1]), w1 = f2bf(c[2]), w2 = f2bf(c[3]),
                   w3 = f2bf(c[4]), w4 = f2bf(c[5]), w5 = f2bf(base_w[idx]);
    unsigned int* d = (unsigned int*)(W + (size_t)idx * 6);
    d[0] = w0 | ((unsigned int)w1 << 16);
    d[1] = w2 | ((unsigned int)w3 << 16);
    d[2] = w4 | ((unsigned int)w5 << 16);
}

__global__ __launch_bounds__(256) void prep_bias_kernel(
    const float* __restrict__ coeff, const float* __restrict__ bias,
    float* __restrict__ bp, int I)
{
    int o = blockIdx.x, tid = threadIdx.x;
    float s = 0.f;
    for (int i = tid; i < I; i += 256) s += coeff[((size_t)o * I + i) * 6];
    #pragma unroll
    for (int off = 32; off > 0; off >>= 1) s += __shfl_down(s, off);
    __shared__ float red[4];
    int lane = tid & 63, wv = tid >> 6;
    if (lane == 0) red[wv] = s;
    __syncthreads();
    if (tid == 0) bp[o] = bias[o] + red[0] + red[1] + red[2] + red[3];
}

// ---------------- expand1: x[b,1024] -> Xaug[b,6144] bf16  (block per row) ---
__global__ __launch_bounds__(256) void expand1_kernel(
    const float* __restrict__ x, unsigned short* __restrict__ Xa)
{
    int b = blockIdx.x, tid = threadIdx.x;
    f32x4 xv = *(const f32x4*)(x + (size_t)b * 1024 + tid * 4);
    alignas(16) unsigned short ov[24];
    #pragma unroll
    for (int e = 0; e < 4; e++) cheb_pack(fast_tanh(xv[e]), ov + e * 6);
    u16x8* dst = (u16x8*)(Xa + (size_t)b * 6144 + tid * 24);
    const u16x8* src = (const u16x8*)ov;
    dst[0] = src[0]; dst[1] = src[1]; dst[2] = src[2];
}

// ------------- LN + SiLU + expand2 fused (block per row of 1024, h in bf16) --
__global__ __launch_bounds__(256) void ln_silu_expand_kernel(
    const unsigned short* __restrict__ H, const float* __restrict__ gamma,
    const float* __restrict__ beta, unsigned short* __restrict__ Xa)
{
    int b = blockIdx.x, tid = threadIdx.x;
    ushort4 hb = *(const ushort4*)(H + (size_t)b * 1024 + tid * 4);
    float hv[4] = { bf2f(hb.x), bf2f(hb.y), bf2f(hb.z), bf2f(hb.w) };
    float s1 = hv[0] + hv[1] + hv[2] + hv[3];
    float s2 = hv[0]*hv[0] + hv[1]*hv[1] + hv[2]*hv[2] + hv[3]*hv[3];
    #pragma unroll
    for (int off = 32; off > 0; off >>= 1) {
        s1 += __shfl_down(s1, off);
        s2 += __shfl_down(s2, off);
    }
    __shared__ float red[8];
    __shared__ float stats[2];
    int lane = tid & 63, wv = tid >> 6;
    if (lane == 0) { red[wv] = s1; red[4 + wv] = s2; }
    __syncthreads();
    if (tid == 0) {
        float t1 = red[0] + red[1] + red[2] + red[3];
        float t2 = red[4] + red[5] + red[6] + red[7];
        float mu = t1 * (1.f / 1024.f);
        float var = t2 * (1.f / 1024.f) - mu * mu;
        stats[0] = mu;
        stats[1] = rsqrtf(var + 1e-5f);
    }
    __syncthreads();
    float mu = stats[0], rs = stats[1];
    f32x4 g  = *(const f32x4*)(gamma + tid * 4);
    f32x4 bt = *(const f32x4*)(beta  + tid * 4);
    alignas(16) unsigned short ov[24];
    #pragma unroll
    for (int e = 0; e < 4; e++) {
        float y = (hv[e] - mu) * rs * g[e] + bt[e];
        cheb_pack(fast_silu(y), ov + e * 6);
    }
    u16x8* dst = (u16x8*)(Xa + (size_t)b * 6144 + tid * 24);
    const u16x8* src = (const u16x8*)ov;
    dst[0] = src[0]; dst[1] = src[1]; dst[2] = src[2];
}

// ==== ring-4 pipelined bf16 GEMM: C[M,N] = A[M,K]*W[N,K]^T + bias (BK=32) ===
// 256 x BN tile, 8 waves (2M x 4N), wave tile 128 x (BN/4).

template<int BN, bool OUT_BF16>
__global__ __launch_bounds__(512, 2) void gemm4_kernel(
    const unsigned short* __restrict__ A,   // [M,K] bf16 bits
    const unsigned short* __restrict__ Wt,  // [N,K] bf16 bits
    const float* __restrict__ bias,         // [N]
    void* __restrict__ Cout,                // [M,N] bf16 or f32
    int N, int K, int NMT)
{
    constexpr int FN  = BN / 64;        // B frags per wave (4 or 2)
    constexpr int LPS = 2 + BN / 128;   // gload_lds per wave per stage (4 or 3)
    constexpr int ASZ = 256 * 32;       // shorts per A ring slot (16 KB)
    constexpr int BSZ = BN * 32;        // shorts per B ring slot
    __shared__ __align__(16) unsigned short As[4 * ASZ];
    __shared__ __align__(16) unsigned short Bs[4 * BSZ];

    const int tid  = threadIdx.x;
    const int lane = tid & 63;
    const int wave = tid >> 6;
    const int wm   = wave >> 2;         // 0..1
    const int wn   = wave & 3;          // 0..3

    // bijective XCD swizzle (grid % 8 == 0 here)
    int wg = blockIdx.x;
    {
        const int nwg = gridDim.x;
        if ((nwg & 7) == 0) { const int cpx = nwg >> 3; wg = (wg & 7) * cpx + (wg >> 3); }
    }
    const int mt = wg % NMT;
    const int nt = wg / NMT;
    const size_t m0 = (size_t)mt * 256;
    const size_t n0 = (size_t)nt * BN;

    // ---- staging addressing: pre-swizzled global src, linear LDS dest ----
    // 16-row unit u; thread covers (row = u*16 + lane/4, chunk = lane%4),
    // src chunk = (lane&3) ^ ((row>>1)&3) = (lane&3) ^ ((lane>>3)&3).
    const int cs   = (((lane & 3) ^ ((lane >> 3) & 3)) << 3);  // shorts
    const int srow = lane >> 2;
    const unsigned short* AgJ0 = A + (m0 + (size_t)((wave * 2 + 0) * 16 + srow)) * K + cs;
    const unsigned short* AgJ1 = A + (m0 + (size_t)((wave * 2 + 1) * 16 + srow)) * K + cs;
    const unsigned short* BgJ0 = Wt + (n0 + (size_t)((wave * (BN / 128) + 0) * 16 + srow)) * K + cs;
    const unsigned short* BgJ1 = (BN == 256)
        ? Wt + (n0 + (size_t)((wave * 2 + 1) * 16 + srow)) * K + cs : BgJ0;
    unsigned short* AD0 = As + (wave * 2 + 0) * 512 + lane * 8;
    unsigned short* AD1 = As + (wave * 2 + 1) * 512 + lane * 8;
    unsigned short* BD0 = Bs + (wave * (BN / 128) + 0) * 512 + lane * 8;
    unsigned short* BD1 = Bs + (wave * 2 + 1) * 512 + lane * 8;   // BN=256 only

    // ---- frag-read bases (XOR de-swizzle on read; key = (row>>1)&3) ----
    const int fr = lane & 15;
    const int cg = lane >> 4;
    const int ck = ((cg ^ ((fr >> 1) & 3)) << 3);               // shorts
    const unsigned short* PA = As + (wm * 128 + fr) * 32 + ck;
    const unsigned short* PB = Bs + (wn * (BN / 4) + fr) * 32 + ck;

    const int NT = K >> 5;              // 32-wide K-tiles (192 here, %4==0)

    f32x4 acc[2][4][FN];
    #pragma unroll
    for (int mh = 0; mh < 2; ++mh)
        #pragma unroll
        for (int mf = 0; mf < 4; ++mf)
            #pragma unroll
            for (int nf = 0; nf < FN; ++nf)
                acc[mh][mf][nf] = f32x4{0.f, 0.f, 0.f, 0.f};

    bf16x8 aF[8], aG[8], bF[FN], bG[FN];

#define STAGE(T, R_) do { \
    const size_t ko_ = (size_t)(T) * 32; \
    load_lds16(AgJ0 + ko_, AD0 + (R_) * ASZ); \
    load_lds16(AgJ1 + ko_, AD1 + (R_) * ASZ); \
    load_lds16(BgJ0 + ko_, BD0 + (R_) * BSZ); \
    if constexpr (BN == 256) load_lds16(BgJ1 + ko_, BD1 + (R_) * BSZ); \
} while (0)

#define RD(AF_, BF_, R_) do { \
    _Pragma("unroll") \
    for (int mh = 0; mh < 2; ++mh) \
        _Pragma("unroll") \
        for (int mf = 0; mf < 4; ++mf) \
            AF_[mh * 4 + mf] = *(const bf16x8*)(PA + (R_) * ASZ + (mh * 64 + mf * 16) * 32); \
    _Pragma("unroll") \
    for (int nf = 0; nf < FN; ++nf) \
        BF_[nf] = *(const bf16x8*)(PB + (R_) * BSZ + nf * 16 * 32); \
} while (0)

#define MM(AF_, BF_) do { \
    _Pragma("unroll") \
    for (int mh = 0; mh < 2; ++mh) \
        _Pragma("unroll") \
        for (int mf = 0; mf < 4; ++mf) \
            _Pragma("unroll") \
            for (int nf = 0; nf < FN; ++nf) \
                acc[mh][mf][nf] = __builtin_amdgcn_mfma_f32_16x16x32_bf16( \
                    AF_[mh * 4 + mf], BF_[nf], acc[mh][mf][nf], 0, 0, 0); \
} while (0)

// counted steady wait: drain stage(t+1), leave 2 stages (2*LPS loads) in flight
#define WSTEADY() do { \
    if constexpr (BN == 256) asm volatile("s_waitcnt vmcnt(8) lgkmcnt(0)" ::: "memory"); \
    else                     asm volatile("s_waitcnt vmcnt(6) lgkmcnt(0)" ::: "memory"); \
    __builtin_amdgcn_s_barrier(); } while (0)
#define WTAIL1() do { \
    if constexpr (BN == 256) asm volatile("s_waitcnt vmcnt(4) lgkmcnt(0)" ::: "memory"); \
    else                     asm volatile("s_waitcnt vmcnt(3) lgkmcnt(0)" ::: "memory"); \
    __builtin_amdgcn_s_barrier(); } while (0)
#define WTAIL0() do { \
    asm volatile("s_waitcnt vmcnt(0) lgkmcnt(0)" ::: "memory"); \
    __builtin_amdgcn_s_barrier(); } while (0)

    // prologue: stage T0..T3 into ring 0..3; drain T0 only; read frags(T0)
    STAGE(0, 0); STAGE(1, 1); STAGE(2, 2); STAGE(3, 3);
    if constexpr (BN == 256) asm volatile("s_waitcnt vmcnt(12)" ::: "memory");
    else                     asm volatile("s_waitcnt vmcnt(9)" ::: "memory");
    __builtin_amdgcn_s_barrier();
    RD(aF, bF, 0);

    // main: bodies 0..NT-5 (all stage t+4); unroll x4 for constant ring idx
    for (int t = 0; t < NT - 4; t += 4) {
        WSTEADY(); RD(aG, bG, 1); STAGE(t + 4, 0); MM(aF, bF);   // body t+0
        WSTEADY(); RD(aF, bF, 2); STAGE(t + 5, 1); MM(aG, bG);   // body t+1
        WSTEADY(); RD(aG, bG, 3); STAGE(t + 6, 2); MM(aF, bF);   // body t+2
        WSTEADY(); RD(aF, bF, 0); STAGE(t + 7, 3); MM(aG, bG);   // body t+3
    }
    // tail: bodies NT-4..NT-1 (no staging; drain 2L -> L -> 0)
    WSTEADY(); RD(aG, bG, 1); MM(aF, bF);   // body NT-4 (drains stage NT-3)
    WTAIL1();  RD(aF, bF, 2); MM(aG, bG);   // body NT-3 (drains stage NT-2)
    WTAIL0();  RD(aG, bG, 3); MM(aF, bF);   // body NT-2 (drains stage NT-1)
    MM(aG, bG);                             // body NT-1 (compiler lgkm waits)

#undef STAGE
#undef RD
#undef MM
#undef WSTEADY
#undef WTAIL1
#undef WTAIL0

    // C/D layout (verified): col = lane&15, row = (lane>>4)*4 + reg
    const size_t rbase0 = m0 + wm * 128 + ((lane >> 4) << 2);
    const int cb = lane & 15;
    int colg[FN]; float bv[FN];
    #pragma unroll
    for (int nf = 0; nf < FN; ++nf) {
        colg[nf] = (int)n0 + wn * (BN / 4) + nf * 16 + cb;
        bv[nf] = bias[colg[nf]];
    }
    #pragma unroll
    for (int mh = 0; mh < 2; ++mh)
        #pragma unroll
        for (int mf = 0; mf < 4; ++mf) {
            const size_t rg0 = rbase0 + mh * 64 + mf * 16;
            #pragma unroll
            for (int r = 0; r < 4; ++r) {
                const size_t rowoff = (rg0 + r) * (size_t)N;
                #pragma unroll
                for (int nf = 0; nf < FN; ++nf) {
                    const float v = acc[mh][mf][nf][r] + bv[nf];
                    if constexpr (OUT_BF16)
                        ((unsigned short*)Cout)[rowoff + colg[nf]] = f2bf(v);
                    else
                        ((float*)Cout)[rowoff + colg[nf]] = v;
                }
            }
        }
}

extern "C" void kernel_launch(void* const* d_in, const int* in_sizes, int n_in,
                              void* d_out, int out_size, void* d_ws, size_t ws_size,
                              hipStream_t stream)
{
    const float* x       = (const float*)d_in[0];
    const float* coeff1  = (const float*)d_in[1];
    const float* base_w1 = (const float*)d_in[2];
    const float* bias1   = (const float*)d_in[3];
    const float* gamma   = (const float*)d_in[4];
    const float* beta    = (const float*)d_in[5];
    const float* coeff2  = (const float*)d_in[6];
    const float* base_w2 = (const float*)d_in[7];
    const float* bias2   = (const float*)d_in[8];
    float* out = (float*)d_out;

    const int B = 16384, D0 = 1024, D1 = 1024, D2 = 512;
    const int K1 = D0 * 6, K2 = D1 * 6;   // 6144 each

    char* base = (char*)d_ws;
    size_t off = 0;
    unsigned short* W1 = (unsigned short*)(base + off); off += (size_t)D1 * K1 * 2;
    unsigned short* W2 = (unsigned short*)(base + off); off += (size_t)D2 * K2 * 2;
    float* b1p = (float*)(base + off); off += (size_t)D1 * 4;
    float* b2p = (float*)(base + off); off += (size_t)D2 * 4;
    off = (off + 255) & ~(size_t)255;

    size_t per_row = (size_t)K1 * 2 + (size_t)D1 * 2;   // 14336 B
    long long avail = (long long)ws_size - (long long)off;
    long long mcl = avail > 0 ? avail / (long long)per_row : 0;
    int Mc = (int)((mcl / 256) * 256);
    if (Mc < 256) Mc = 256;
    if (Mc > B) Mc = B;

    unsigned short* Xa = (unsigned short*)(base + off);
    unsigned short* h = (unsigned short*)(base + off + (size_t)Mc * K1 * 2);

    prep_w_kernel<<<(D1 * D0 + 255) / 256, 256, 0, stream>>>(coeff1, base_w1, W1, D1 * D0);
    prep_w_kernel<<<(D2 * D1 + 255) / 256, 256, 0, stream>>>(coeff2, base_w2, W2, D2 * D1);
    prep_bias_kernel<<<D1, 256, 0, stream>>>(coeff1, bias1, b1p, D0);
    prep_bias_kernel<<<D2, 256, 0, stream>>>(coeff2, bias2, b2p, D1);

    for (int m0 = 0; m0 < B; m0 += Mc) {
        int rows = (B - m0 < Mc) ? (B - m0) : Mc;
        int nmt = rows / 256;
        expand1_kernel<<<rows, 256, 0, stream>>>(x + (size_t)m0 * D0, Xa);
        gemm4_kernel<256, true><<<nmt * (D1 / 256), 512, 0, stream>>>(
            Xa, W1, b1p, h, D1, K1, nmt);
        ln_silu_expand_kernel<<<rows, 256, 0, stream>>>(h, gamma, beta, Xa);
        gemm4_kernel<128, false><<<nmt * (D2 / 128), 512, 0, stream>>>(
            Xa, W2, b2p, out + (size_t)m0 * D2, D2, K2, nmt);
    }
}